// Round 1
// baseline (409.712 us; speedup 1.0000x reference)
//
#include <hip/hip_runtime.h>
#include <hip/hip_bf16.h>
#include <math.h>

#define HW 4096
#define NC 256
#define NB 8
#define NA 5
#define NIT 96
#define SCL 0.0625f

// workspace layout (float offsets)
#define OFF_WQK   0                        // 256*256
#define OFF_CNT   (OFF_WQK + 65536)        // 16
#define OFF_FG    (OFF_CNT + 16)           // 8*4096
#define OFF_PROTO (OFF_FG + 32768)         // 2*8*256
#define OFF_QK    (OFF_PROTO + 4096)       // 2*8*5*256
#define OFF_L     (OFF_QK + 20480)         // 2*8*5*4096
#define OFF_P     (OFF_L + 327680)         // 2*8*5*4096
#define OFF_PS    (OFF_P + 327680)         // 2*8*5*256
#define OFF_W2    (OFF_PS + 20480)         // 8*10*4096

template<int NV, int NW>
__device__ inline void blockReduceSumN(float (&v)[NV], float* lds, int tid) {
    __syncthreads();
    int lane = tid & 63, wid = tid >> 6;
    #pragma unroll
    for (int off = 32; off > 0; off >>= 1)
        #pragma unroll
        for (int k = 0; k < NV; ++k) v[k] += __shfl_xor(v[k], off, 64);
    if (lane == 0) {
        #pragma unroll
        for (int k = 0; k < NV; ++k) lds[wid * NV + k] = v[k];
    }
    __syncthreads();
    if (tid == 0) {
        #pragma unroll
        for (int k = 0; k < NV; ++k) {
            float s = 0.f;
            for (int w = 0; w < NW; ++w) s += lds[w * NV + k];
            lds[k] = s;
        }
    }
    __syncthreads();
    #pragma unroll
    for (int k = 0; k < NV; ++k) v[k] = lds[k];
}

template<int NV, int NW>
__device__ inline void blockReduceMaxN(float (&v)[NV], float* lds, int tid) {
    __syncthreads();
    int lane = tid & 63, wid = tid >> 6;
    #pragma unroll
    for (int off = 32; off > 0; off >>= 1)
        #pragma unroll
        for (int k = 0; k < NV; ++k) v[k] = fmaxf(v[k], __shfl_xor(v[k], off, 64));
    if (lane == 0) {
        #pragma unroll
        for (int k = 0; k < NV; ++k) lds[wid * NV + k] = v[k];
    }
    __syncthreads();
    if (tid == 0) {
        #pragma unroll
        for (int k = 0; k < NV; ++k) {
            float s = -3.0e38f;
            for (int w = 0; w < NW; ++w) s = fmaxf(s, lds[w * NV + k]);
            lds[k] = s;
        }
    }
    __syncthreads();
    #pragma unroll
    for (int k = 0; k < NV; ++k) v[k] = lds[k];
}

// blocks 0..15: mask counts; blocks 16..143: fg thresholded softmax channel 1
__global__ __launch_bounds__(256) void k_prep(const int* __restrict__ m1, const int* __restrict__ m2,
                                              const float* __restrict__ qpred, float* __restrict__ ws) {
    __shared__ float lds[8];
    int bid = blockIdx.x, tid = threadIdx.x;
    if (bid < 16) {
        int s = bid >> 3, b = bid & 7;
        const int* m = s ? m2 : m1;
        float cnt[1] = {0.f};
        for (int j = 0; j < 16; ++j)
            cnt[0] += (m[b * HW + tid + j * 256] == 1) ? 1.f : 0.f;
        blockReduceSumN<1, 4>(cnt, lds, tid);
        if (tid == 0) ws[OFF_CNT + bid] = cnt[0];
    } else {
        int idx = bid - 16;
        int b = idx >> 4, tile = idx & 15;
        int n = tile * 256 + tid;
        float p0 = qpred[(size_t)(b * 2 + 0) * HW + n];
        float p1 = qpred[(size_t)(b * 2 + 1) * HW + n];
        float f = 1.f / (1.f + expf(p0 - p1));   // softmax channel 1
        if (f > 0.7f) f = 1.f;
        else if (f < 0.3f) f = 0.f;
        ws[OFF_FG + b * HW + n] = f;
    }
}

// Wqk[c1][c2] = sum_cp Wq[cp][c1]*Wk[cp][c2]
__global__ __launch_bounds__(256) void k_wqk(const float* __restrict__ Wq, const float* __restrict__ Wk,
                                             float* __restrict__ ws) {
    int c1 = blockIdx.x, c2 = threadIdx.x;
    float acc = 0.f;
    for (int cp = 0; cp < NC; ++cp)
        acc += Wq[cp * NC + c1] * Wk[cp * NC + c2];
    ws[OFF_WQK + c1 * NC + c2] = acc;
}

// proto[s][b][c] = masked mean over HW
__global__ __launch_bounds__(256) void k_proto(const float* __restrict__ f1, const float* __restrict__ f2,
                                               const int* __restrict__ m1, const int* __restrict__ m2,
                                               float* __restrict__ ws) {
    __shared__ float lds[8];
    int bid = blockIdx.x, tid = threadIdx.x;
    int s = bid >> 11, rem = bid & 2047, b = rem >> 8, c = rem & 255;
    const float* f = s ? f2 : f1;
    const int* m = s ? m2 : m1;
    const float* fb = f + ((size_t)b * NC + c) * HW;
    const int* mb = m + b * HW;
    float acc[1] = {0.f};
    for (int j = 0; j < 16; ++j) {
        int n = tid + j * 256;
        if (mb[n] == 1) acc[0] += fb[n];
    }
    blockReduceSumN<1, 4>(acc, lds, tid);
    if (tid == 0) {
        float cnt = ws[OFF_CNT + s * 8 + b];
        ws[OFF_PROTO + (s * 8 + b) * NC + c] = acc[0] / (cnt + 1e-5f);
    }
}

// qk[a][cout] = sum_cin (proto[cin]+tok[a][cin]) * Wqk[cin][cout]
__global__ __launch_bounds__(256) void k_qk(const float* __restrict__ tok, float* __restrict__ ws) {
    __shared__ float sp3[NA * NC];
    int sb = blockIdx.x, tid = threadIdx.x;
    const float* proto = ws + OFF_PROTO + sb * NC;
    for (int i = tid; i < NA * NC; i += 256) {
        int c = i & 255;
        sp3[i] = proto[c] + tok[i];
    }
    __syncthreads();
    const float* wqk = ws + OFF_WQK;
    float acc[NA] = {0, 0, 0, 0, 0};
    for (int cin = 0; cin < NC; ++cin) {
        float w = wqk[cin * NC + tid];
        #pragma unroll
        for (int a = 0; a < NA; ++a) acc[a] += sp3[a * NC + cin] * w;
    }
    float* qko = ws + OFF_QK + sb * NA * NC;
    #pragma unroll
    for (int a = 0; a < NA; ++a) qko[a * NC + tid] = acc[a];
}

// L[s][b][a][n] = sum_c qk[a][c]*feat[c][n]
__global__ __launch_bounds__(256) void k_attnlog(const float* __restrict__ f1, const float* __restrict__ f2,
                                                 float* __restrict__ ws) {
    __shared__ float sqk[NA * NC];
    int bid = blockIdx.x, tid = threadIdx.x;
    int s = bid >> 7, b = (bid >> 4) & 7, tile = bid & 15;
    const float* f = s ? f2 : f1;
    int sb = s * 8 + b;
    const float* qkb = ws + OFF_QK + sb * NA * NC;
    for (int i = tid; i < NA * NC; i += 256) sqk[i] = qkb[i];
    __syncthreads();
    int n = tile * 256 + tid;
    const float* fb = f + (size_t)b * NC * HW + n;
    float acc[NA] = {0, 0, 0, 0, 0};
    for (int c = 0; c < NC; ++c) {
        float v = fb[(size_t)c * HW];
        #pragma unroll
        for (int a = 0; a < NA; ++a) acc[a] += sqk[a * NC + c] * v;
    }
    float* Lb = ws + OFF_L + (size_t)sb * NA * HW;
    #pragma unroll
    for (int a = 0; a < NA; ++a) Lb[a * HW + n] = acc[a];
}

// masked softmax -> K=exp(2*attn-2)*mask -> 96 sinkhorn iters -> plan
__global__ __launch_bounds__(1024) void k_sinkhorn(const int* __restrict__ m1, const int* __restrict__ m2,
                                                   float* __restrict__ ws) {
    __shared__ float lds[16 * NA];
    int sb = blockIdx.x, tid = threadIdx.x;
    int s = sb >> 3, b = sb & 7;
    const int* m = s ? m2 : m1;
    float* Lb = ws + OFF_L + (size_t)sb * NA * HW;
    float mk[4], l[NA][4], K[NA][4];
    #pragma unroll
    for (int j = 0; j < 4; ++j) {
        int n = tid + j * 1024;
        mk[j] = (m[b * HW + n] == 1) ? 1.f : 0.f;
        #pragma unroll
        for (int a = 0; a < NA; ++a) l[a][j] = Lb[a * HW + n];
    }
    float r[NA];
    #pragma unroll
    for (int a = 0; a < NA; ++a) {
        float mx = -3.0e38f;
        #pragma unroll
        for (int j = 0; j < 4; ++j) if (mk[j] > 0.f) mx = fmaxf(mx, l[a][j]);
        r[a] = mx;
    }
    blockReduceMaxN<NA, 16>(r, lds, tid);
    float rs[NA];
    #pragma unroll
    for (int a = 0; a < NA; ++a) {
        float sum = 0.f;
        #pragma unroll
        for (int j = 0; j < 4; ++j) {
            float e = (mk[j] > 0.f) ? expf(l[a][j] - r[a]) : 0.f;
            l[a][j] = e; sum += e;
        }
        rs[a] = sum;
    }
    blockReduceSumN<NA, 16>(rs, lds, tid);
    float cnt = ws[OFF_CNT + sb];
    float bcol[4];
    #pragma unroll
    for (int j = 0; j < 4; ++j) bcol[j] = mk[j] / cnt;
    #pragma unroll
    for (int a = 0; a < NA; ++a)
        #pragma unroll
        for (int j = 0; j < 4; ++j)
            K[a][j] = mk[j] * expf(2.f * (l[a][j] / rs[a]) - 2.f);
    float u[NA];
    #pragma unroll
    for (int a = 0; a < NA; ++a) u[a] = 0.2f;
    for (int it = 0; it < NIT; ++it) {
        float part[NA] = {0, 0, 0, 0, 0};
        #pragma unroll
        for (int j = 0; j < 4; ++j) {
            float d = 0.f;
            #pragma unroll
            for (int a = 0; a < NA; ++a) d += K[a][j] * u[a];
            float t = bcol[j] / fmaxf(d, 1e-30f);
            #pragma unroll
            for (int a = 0; a < NA; ++a) part[a] += K[a][j] * t;
        }
        blockReduceSumN<NA, 16>(part, lds, tid);
        #pragma unroll
        for (int a = 0; a < NA; ++a) u[a] = 0.2f / fmaxf(part[a], 1e-30f);
    }
    float* Pb = ws + OFF_P + (size_t)sb * NA * HW;
    #pragma unroll
    for (int j = 0; j < 4; ++j) {
        float d = 0.f;
        #pragma unroll
        for (int a = 0; a < NA; ++a) d += K[a][j] * u[a];
        float t = bcol[j] / fmaxf(d, 1e-30f);
        int n = tid + j * 1024;
        #pragma unroll
        for (int a = 0; a < NA; ++a) Pb[a * HW + n] = u[a] * K[a][j] * t;
    }
}

// ps[s][b][a][c] = sum_n P[a][n]*feat[c][n]
__global__ __launch_bounds__(256) void k_ps(const float* __restrict__ f1, const float* __restrict__ f2,
                                            float* __restrict__ ws) {
    __shared__ float lds[4 * NA];
    int bid = blockIdx.x, tid = threadIdx.x;
    int s = bid >> 11, rem = bid & 2047, b = rem >> 8, c = rem & 255;
    const float* f = s ? f2 : f1;
    int sb = s * 8 + b;
    const float* fb = f + ((size_t)b * NC + c) * HW;
    const float* Pb = ws + OFF_P + (size_t)sb * NA * HW;
    float acc[NA] = {0, 0, 0, 0, 0};
    for (int j = 0; j < 16; ++j) {
        int n = tid + j * 256;
        float v = fb[n];
        #pragma unroll
        for (int a = 0; a < NA; ++a) acc[a] += Pb[a * HW + n] * v;
    }
    blockReduceSumN<NA, 4>(acc, lds, tid);
    if (tid == 0) {
        float* ps = ws + OFF_PS + sb * NA * NC;
        #pragma unroll
        for (int a = 0; a < NA; ++a) ps[a * NC + c] = acc[a];
    }
}

// mem rows 0..9: proto3 + ps @ Wv^T
__global__ __launch_bounds__(256) void k_outproto(const float* __restrict__ Wv, const float* __restrict__ tok,
                                                  float* __restrict__ ws, float* __restrict__ out) {
    __shared__ float sps[NA * NC];
    int sb = blockIdx.x, tid = threadIdx.x;
    int s = sb >> 3, b = sb & 7;
    const float* ps = ws + OFF_PS + sb * NA * NC;
    for (int i = tid; i < NA * NC; i += 256) sps[i] = ps[i];
    __syncthreads();
    float acc[NA] = {0, 0, 0, 0, 0};
    const float* wr = Wv + tid * NC;
    for (int c = 0; c < NC; ++c) {
        float w = wr[c];
        #pragma unroll
        for (int a = 0; a < NA; ++a) acc[a] += sps[a * NC + c] * w;
    }
    float p = ws[OFF_PROTO + sb * NC + tid];
    #pragma unroll
    for (int a = 0; a < NA; ++a)
        out[(size_t)b * 20 * NC + (s * NA + a) * NC + tid] = p + tok[a * NC + tid] + acc[a];
}

// attn2 logits: SCL * fg[n] * sum_c curr[i][c]*qfeat[c][n]
__global__ __launch_bounds__(256) void k_attn2log(const float* __restrict__ qf, const float* __restrict__ out,
                                                  float* __restrict__ ws) {
    __shared__ float scurr[10 * NC];
    int bid = blockIdx.x, tid = threadIdx.x;
    int b = bid >> 4, tile = bid & 15;
    const float* cb = out + (size_t)b * 20 * NC;
    for (int i = tid; i < 10 * NC; i += 256) scurr[i] = cb[i];
    __syncthreads();
    int n = tile * 256 + tid;
    const float* fb = qf + (size_t)b * NC * HW + n;
    float acc[10] = {0, 0, 0, 0, 0, 0, 0, 0, 0, 0};
    for (int c = 0; c < NC; ++c) {
        float v = fb[(size_t)c * HW];
        #pragma unroll
        for (int i = 0; i < 10; ++i) acc[i] += scurr[i * NC + c] * v;
    }
    float fgv = ws[OFF_FG + b * HW + n] * SCL;
    float* al = ws + OFF_W2 + (size_t)b * 10 * HW;
    #pragma unroll
    for (int i = 0; i < 10; ++i) al[i * HW + n] = acc[i] * fgv;
}

// softmax over full 4096 row, then multiply by fg (folds the qf masking for apply)
__global__ __launch_bounds__(256) void k_softmax2(float* __restrict__ ws) {
    __shared__ float lds[8];
    int row = blockIdx.x, tid = threadIdx.x;
    int b = row / 10;
    float* al = ws + OFF_W2 + (size_t)row * HW;
    float vals[16];
    float mx[1] = {-3.0e38f};
    #pragma unroll
    for (int j = 0; j < 16; ++j) {
        vals[j] = al[tid + j * 256];
        mx[0] = fmaxf(mx[0], vals[j]);
    }
    blockReduceMaxN<1, 4>(mx, lds, tid);
    float sum[1] = {0.f};
    #pragma unroll
    for (int j = 0; j < 16; ++j) {
        vals[j] = expf(vals[j] - mx[0]);
        sum[0] += vals[j];
    }
    blockReduceSumN<1, 4>(sum, lds, tid);
    float inv = 1.f / sum[0];
    const float* fg = ws + OFF_FG + b * HW;
    #pragma unroll
    for (int j = 0; j < 16; ++j) {
        int n = tid + j * 256;
        al[n] = vals[j] * inv * fg[n];
    }
}

// mem rows 10..19: curr + sum_n w2[i][n]*qfeat[c][n]
__global__ __launch_bounds__(256) void k_apply2(const float* __restrict__ qf, float* __restrict__ ws,
                                                float* __restrict__ out) {
    __shared__ float lds[4 * 10];
    int bid = blockIdx.x, tid = threadIdx.x;
    int b = bid >> 8, c = bid & 255;
    const float* fb = qf + ((size_t)b * NC + c) * HW;
    const float* w2 = ws + OFF_W2 + (size_t)b * 10 * HW;
    float acc[10] = {0, 0, 0, 0, 0, 0, 0, 0, 0, 0};
    for (int j = 0; j < 16; ++j) {
        int n = tid + j * 256;
        float v = fb[n];
        #pragma unroll
        for (int i = 0; i < 10; ++i) acc[i] += w2[(size_t)i * HW + n] * v;
    }
    blockReduceSumN<10, 4>(acc, lds, tid);
    if (tid == 0) {
        float* ob = out + (size_t)b * 20 * NC;
        #pragma unroll
        for (int i = 0; i < 10; ++i)
            ob[(10 + i) * NC + c] = ob[i * NC + c] + acc[i];
    }
}

// curr_prototype = mean over 20 mem rows
__global__ __launch_bounds__(256) void k_mean(float* __restrict__ out) {
    int b = blockIdx.x, c = threadIdx.x;
    const float* ob = out + (size_t)b * 20 * NC;
    float s = 0.f;
    #pragma unroll
    for (int i = 0; i < 20; ++i) s += ob[i * NC + c];
    out[40960 + b * NC + c] = s * 0.05f;
}

extern "C" void kernel_launch(void* const* d_in, const int* in_sizes, int n_in,
                              void* d_out, int out_size, void* d_ws, size_t ws_size,
                              hipStream_t stream) {
    const float* f1  = (const float*)d_in[0];
    const float* f2  = (const float*)d_in[1];
    const int*   m1  = (const int*)d_in[2];
    const int*   m2  = (const int*)d_in[3];
    const float* qf  = (const float*)d_in[4];
    const float* qp  = (const float*)d_in[5];
    const float* Wq  = (const float*)d_in[6];
    const float* Wk  = (const float*)d_in[7];
    const float* Wv  = (const float*)d_in[8];
    const float* tok = (const float*)d_in[9];
    float* out = (float*)d_out;
    float* ws  = (float*)d_ws;

    k_prep<<<144, 256, 0, stream>>>(m1, m2, qp, ws);
    k_wqk<<<256, 256, 0, stream>>>(Wq, Wk, ws);
    k_proto<<<4096, 256, 0, stream>>>(f1, f2, m1, m2, ws);
    k_qk<<<16, 256, 0, stream>>>(tok, ws);
    k_attnlog<<<256, 256, 0, stream>>>(f1, f2, ws);
    k_sinkhorn<<<16, 1024, 0, stream>>>(m1, m2, ws);
    k_ps<<<4096, 256, 0, stream>>>(f1, f2, ws);
    k_outproto<<<16, 256, 0, stream>>>(Wv, tok, ws, out);
    k_attn2log<<<128, 256, 0, stream>>>(qf, out, ws);
    k_softmax2<<<80, 256, 0, stream>>>(ws);
    k_apply2<<<2048, 256, 0, stream>>>(qf, ws, out);
    k_mean<<<8, 256, 0, stream>>>(out);
}

// Round 2
// 215.223 us; speedup vs baseline: 1.9037x; 1.9037x over previous
//
#include <hip/hip_runtime.h>
#include <hip/hip_bf16.h>
#include <math.h>

#define HW 4096
#define NC 256
#define NB 8
#define NA 5
#define NIT 48
#define SCL 0.0625f

// workspace layout (float offsets)
#define OFF_WQK   0                        // 256*256
#define OFF_CNT   (OFF_WQK + 65536)        // 16
#define OFF_FG    (OFF_CNT + 16)           // 8*4096
#define OFF_PROTO (OFF_FG + 32768)         // 2*8*256
#define OFF_QK    (OFF_PROTO + 4096)       // 2*8*5*256
#define OFF_L     (OFF_QK + 20480)         // 2*8*5*4096
#define OFF_P     (OFF_L + 327680)         // 2*8*5*4096
#define OFF_PS    (OFF_P + 327680)         // 2*8*5*256
#define OFF_W2    (OFF_PS + 20480)         // 8*10*4096

template<int NV, int NW>
__device__ inline void blockReduceSumN(float (&v)[NV], float* lds, int tid) {
    __syncthreads();
    int lane = tid & 63, wid = tid >> 6;
    #pragma unroll
    for (int off = 32; off > 0; off >>= 1)
        #pragma unroll
        for (int k = 0; k < NV; ++k) v[k] += __shfl_xor(v[k], off, 64);
    if (lane == 0) {
        #pragma unroll
        for (int k = 0; k < NV; ++k) lds[wid * NV + k] = v[k];
    }
    __syncthreads();
    if (tid == 0) {
        #pragma unroll
        for (int k = 0; k < NV; ++k) {
            float s = 0.f;
            for (int w = 0; w < NW; ++w) s += lds[w * NV + k];
            lds[k] = s;
        }
    }
    __syncthreads();
    #pragma unroll
    for (int k = 0; k < NV; ++k) v[k] = lds[k];
}

template<int NV, int NW>
__device__ inline void blockReduceMaxN(float (&v)[NV], float* lds, int tid) {
    __syncthreads();
    int lane = tid & 63, wid = tid >> 6;
    #pragma unroll
    for (int off = 32; off > 0; off >>= 1)
        #pragma unroll
        for (int k = 0; k < NV; ++k) v[k] = fmaxf(v[k], __shfl_xor(v[k], off, 64));
    if (lane == 0) {
        #pragma unroll
        for (int k = 0; k < NV; ++k) lds[wid * NV + k] = v[k];
    }
    __syncthreads();
    if (tid == 0) {
        #pragma unroll
        for (int k = 0; k < NV; ++k) {
            float s = -3.0e38f;
            for (int w = 0; w < NW; ++w) s = fmaxf(s, lds[w * NV + k]);
            lds[k] = s;
        }
    }
    __syncthreads();
    #pragma unroll
    for (int k = 0; k < NV; ++k) v[k] = lds[k];
}

// ---- fast 4-wave reductions with double-buffered partials (ONE barrier) ----
// Safe under strict phase alternation: between the read of buffer p and its
// next write there is always >= 1 intervening barrier.
template<int NV>
__device__ inline void redSum4(float (&v)[NV], float* buf, int lane, int wid) {
    #pragma unroll
    for (int off = 32; off > 0; off >>= 1)
        #pragma unroll
        for (int k = 0; k < NV; ++k) v[k] += __shfl_xor(v[k], off, 64);
    if (lane == 0) {
        #pragma unroll
        for (int k = 0; k < NV; ++k) buf[wid * NV + k] = v[k];
    }
    __syncthreads();
    #pragma unroll
    for (int k = 0; k < NV; ++k)
        v[k] = buf[k] + buf[NV + k] + buf[2 * NV + k] + buf[3 * NV + k];
}

template<int NV>
__device__ inline void redMax4(float (&v)[NV], float* buf, int lane, int wid) {
    #pragma unroll
    for (int off = 32; off > 0; off >>= 1)
        #pragma unroll
        for (int k = 0; k < NV; ++k) v[k] = fmaxf(v[k], __shfl_xor(v[k], off, 64));
    if (lane == 0) {
        #pragma unroll
        for (int k = 0; k < NV; ++k) buf[wid * NV + k] = v[k];
    }
    __syncthreads();
    #pragma unroll
    for (int k = 0; k < NV; ++k)
        v[k] = fmaxf(fmaxf(buf[k], buf[NV + k]), fmaxf(buf[2 * NV + k], buf[3 * NV + k]));
}

__device__ inline float frcp(float x) { return __builtin_amdgcn_rcpf(x); }

// blocks 0..15: mask counts; blocks 16..143: fg thresholded softmax channel 1
__global__ __launch_bounds__(256) void k_prep(const int* __restrict__ m1, const int* __restrict__ m2,
                                              const float* __restrict__ qpred, float* __restrict__ ws) {
    __shared__ float lds[8];
    int bid = blockIdx.x, tid = threadIdx.x;
    if (bid < 16) {
        int s = bid >> 3, b = bid & 7;
        const int* m = s ? m2 : m1;
        float cnt[1] = {0.f};
        for (int j = 0; j < 16; ++j)
            cnt[0] += (m[b * HW + tid + j * 256] == 1) ? 1.f : 0.f;
        blockReduceSumN<1, 4>(cnt, lds, tid);
        if (tid == 0) ws[OFF_CNT + bid] = cnt[0];
    } else {
        int idx = bid - 16;
        int b = idx >> 4, tile = idx & 15;
        int n = tile * 256 + tid;
        float p0 = qpred[(size_t)(b * 2 + 0) * HW + n];
        float p1 = qpred[(size_t)(b * 2 + 1) * HW + n];
        float f = 1.f / (1.f + expf(p0 - p1));   // softmax channel 1
        if (f > 0.7f) f = 1.f;
        else if (f < 0.3f) f = 0.f;
        ws[OFF_FG + b * HW + n] = f;
    }
}

// Wqk[c1][c2] = sum_cp Wq[cp][c1]*Wk[cp][c2]
__global__ __launch_bounds__(256) void k_wqk(const float* __restrict__ Wq, const float* __restrict__ Wk,
                                             float* __restrict__ ws) {
    int c1 = blockIdx.x, c2 = threadIdx.x;
    float acc = 0.f;
    for (int cp = 0; cp < NC; ++cp)
        acc += Wq[cp * NC + c1] * Wk[cp * NC + c2];
    ws[OFF_WQK + c1 * NC + c2] = acc;
}

// proto[s][b][c] = masked mean over HW
__global__ __launch_bounds__(256) void k_proto(const float* __restrict__ f1, const float* __restrict__ f2,
                                               const int* __restrict__ m1, const int* __restrict__ m2,
                                               float* __restrict__ ws) {
    __shared__ float lds[8];
    int bid = blockIdx.x, tid = threadIdx.x;
    int s = bid >> 11, rem = bid & 2047, b = rem >> 8, c = rem & 255;
    const float* f = s ? f2 : f1;
    const int* m = s ? m2 : m1;
    const float* fb = f + ((size_t)b * NC + c) * HW;
    const int* mb = m + b * HW;
    float acc[1] = {0.f};
    for (int j = 0; j < 16; ++j) {
        int n = tid + j * 256;
        if (mb[n] == 1) acc[0] += fb[n];
    }
    blockReduceSumN<1, 4>(acc, lds, tid);
    if (tid == 0) {
        float cnt = ws[OFF_CNT + s * 8 + b];
        ws[OFF_PROTO + (s * 8 + b) * NC + c] = acc[0] / (cnt + 1e-5f);
    }
}

// qk[a][cout] = sum_cin (proto[cin]+tok[a][cin]) * Wqk[cin][cout]
__global__ __launch_bounds__(256) void k_qk(const float* __restrict__ tok, float* __restrict__ ws) {
    __shared__ float sp3[NA * NC];
    int sb = blockIdx.x, tid = threadIdx.x;
    const float* proto = ws + OFF_PROTO + sb * NC;
    for (int i = tid; i < NA * NC; i += 256) {
        int c = i & 255;
        sp3[i] = proto[c] + tok[i];
    }
    __syncthreads();
    const float* wqk = ws + OFF_WQK;
    float acc[NA] = {0, 0, 0, 0, 0};
    for (int cin = 0; cin < NC; ++cin) {
        float w = wqk[cin * NC + tid];
        #pragma unroll
        for (int a = 0; a < NA; ++a) acc[a] += sp3[a * NC + cin] * w;
    }
    float* qko = ws + OFF_QK + sb * NA * NC;
    #pragma unroll
    for (int a = 0; a < NA; ++a) qko[a * NC + tid] = acc[a];
}

// L[s][b][a][n] = sum_c qk[a][c]*feat[c][n]
__global__ __launch_bounds__(256) void k_attnlog(const float* __restrict__ f1, const float* __restrict__ f2,
                                                 float* __restrict__ ws) {
    __shared__ float sqk[NA * NC];
    int bid = blockIdx.x, tid = threadIdx.x;
    int s = bid >> 7, b = (bid >> 4) & 7, tile = bid & 15;
    const float* f = s ? f2 : f1;
    int sb = s * 8 + b;
    const float* qkb = ws + OFF_QK + sb * NA * NC;
    for (int i = tid; i < NA * NC; i += 256) sqk[i] = qkb[i];
    __syncthreads();
    int n = tile * 256 + tid;
    const float* fb = f + (size_t)b * NC * HW + n;
    float acc[NA] = {0, 0, 0, 0, 0};
    for (int c = 0; c < NC; ++c) {
        float v = fb[(size_t)c * HW];
        #pragma unroll
        for (int a = 0; a < NA; ++a) acc[a] += sqk[a * NC + c] * v;
    }
    float* Lb = ws + OFF_L + (size_t)sb * NA * HW;
    #pragma unroll
    for (int a = 0; a < NA; ++a) Lb[a * HW + n] = acc[a];
}

// masked softmax -> K=exp(2*attn-2)*mask -> NIT sinkhorn iters -> plan
// 256 threads, 16 cols/thread, K in registers, 1 barrier per iteration.
__global__ __launch_bounds__(256) void k_sinkhorn(const int* __restrict__ m1, const int* __restrict__ m2,
                                                  float* __restrict__ ws) {
    __shared__ float buf[2][4 * NA];
    int sb = blockIdx.x, tid = threadIdx.x;
    int lane = tid & 63, wid = tid >> 6;
    int s = sb >> 3, b = sb & 7;
    const int* m = s ? m2 : m1;
    float* Lb = ws + OFF_L + (size_t)sb * NA * HW;

    unsigned mbits = 0;
    float K[NA][16];
    // load logits and mask
    #pragma unroll
    for (int j = 0; j < 16; ++j) {
        int n = tid + j * 256;
        if (m[b * HW + n] == 1) mbits |= (1u << j);
        #pragma unroll
        for (int a = 0; a < NA; ++a) K[a][j] = Lb[a * HW + n];
    }
    // masked row max
    float r[NA];
    #pragma unroll
    for (int a = 0; a < NA; ++a) {
        float mx = -3.0e38f;
        #pragma unroll
        for (int j = 0; j < 16; ++j)
            if ((mbits >> j) & 1) mx = fmaxf(mx, K[a][j]);
        r[a] = mx;
    }
    redMax4<NA>(r, buf[0], lane, wid);
    // masked exp and row sum
    float rs[NA];
    #pragma unroll
    for (int a = 0; a < NA; ++a) {
        float sum = 0.f;
        #pragma unroll
        for (int j = 0; j < 16; ++j) {
            float e = ((mbits >> j) & 1) ? expf(K[a][j] - r[a]) : 0.f;
            K[a][j] = e; sum += e;
        }
        rs[a] = sum;
    }
    redSum4<NA>(rs, buf[1], lane, wid);
    float cnt = ws[OFF_CNT + sb];
    float inv_cnt = frcp(cnt);
    // K = mask * exp(2*attn - 2)
    #pragma unroll
    for (int a = 0; a < NA; ++a) {
        float irs = frcp(rs[a]);
        #pragma unroll
        for (int j = 0; j < 16; ++j) {
            float attn = K[a][j] * irs;
            K[a][j] = ((mbits >> j) & 1) ? expf(2.f * attn - 2.f) : 0.f;
        }
    }
    float u[NA];
    #pragma unroll
    for (int a = 0; a < NA; ++a) u[a] = 0.2f;
    for (int it = 0; it < NIT; ++it) {
        float part[NA] = {0, 0, 0, 0, 0};
        #pragma unroll
        for (int j = 0; j < 16; ++j) {
            float d = 0.f;
            #pragma unroll
            for (int a = 0; a < NA; ++a) d += K[a][j] * u[a];
            // masked-out cols: K==0, so t's value is irrelevant (stays finite)
            float t = inv_cnt * frcp(fmaxf(d, 1e-30f));
            #pragma unroll
            for (int a = 0; a < NA; ++a) part[a] += K[a][j] * t;
        }
        redSum4<NA>(part, buf[it & 1], lane, wid);
        #pragma unroll
        for (int a = 0; a < NA; ++a) u[a] = 0.2f * frcp(fmaxf(part[a], 1e-30f));
    }
    float* Pb = ws + OFF_P + (size_t)sb * NA * HW;
    #pragma unroll
    for (int j = 0; j < 16; ++j) {
        float d = 0.f;
        #pragma unroll
        for (int a = 0; a < NA; ++a) d += K[a][j] * u[a];
        float t = inv_cnt * frcp(fmaxf(d, 1e-30f));
        int n = tid + j * 256;
        #pragma unroll
        for (int a = 0; a < NA; ++a) Pb[a * HW + n] = u[a] * K[a][j] * t;
    }
}

// ps[s][b][a][c] = sum_n P[a][n]*feat[c][n]
__global__ __launch_bounds__(256) void k_ps(const float* __restrict__ f1, const float* __restrict__ f2,
                                            float* __restrict__ ws) {
    __shared__ float lds[4 * NA];
    int bid = blockIdx.x, tid = threadIdx.x;
    int s = bid >> 11, rem = bid & 2047, b = rem >> 8, c = rem & 255;
    const float* f = s ? f2 : f1;
    int sb = s * 8 + b;
    const float* fb = f + ((size_t)b * NC + c) * HW;
    const float* Pb = ws + OFF_P + (size_t)sb * NA * HW;
    float acc[NA] = {0, 0, 0, 0, 0};
    for (int j = 0; j < 16; ++j) {
        int n = tid + j * 256;
        float v = fb[n];
        #pragma unroll
        for (int a = 0; a < NA; ++a) acc[a] += Pb[a * HW + n] * v;
    }
    blockReduceSumN<NA, 4>(acc, lds, tid);
    if (tid == 0) {
        float* ps = ws + OFF_PS + sb * NA * NC;
        #pragma unroll
        for (int a = 0; a < NA; ++a) ps[a * NC + c] = acc[a];
    }
}

// mem rows 0..9: proto3 + ps @ Wv^T
__global__ __launch_bounds__(256) void k_outproto(const float* __restrict__ Wv, const float* __restrict__ tok,
                                                  float* __restrict__ ws, float* __restrict__ out) {
    __shared__ float sps[NA * NC];
    int sb = blockIdx.x, tid = threadIdx.x;
    int s = sb >> 3, b = sb & 7;
    const float* ps = ws + OFF_PS + sb * NA * NC;
    for (int i = tid; i < NA * NC; i += 256) sps[i] = ps[i];
    __syncthreads();
    float acc[NA] = {0, 0, 0, 0, 0};
    const float* wr = Wv + tid * NC;
    for (int c = 0; c < NC; ++c) {
        float w = wr[c];
        #pragma unroll
        for (int a = 0; a < NA; ++a) acc[a] += sps[a * NC + c] * w;
    }
    float p = ws[OFF_PROTO + sb * NC + tid];
    #pragma unroll
    for (int a = 0; a < NA; ++a)
        out[(size_t)b * 20 * NC + (s * NA + a) * NC + tid] = p + tok[a * NC + tid] + acc[a];
}

// attn2 logits: SCL * fg[n] * sum_c curr[i][c]*qfeat[c][n]
__global__ __launch_bounds__(256) void k_attn2log(const float* __restrict__ qf, const float* __restrict__ out,
                                                  float* __restrict__ ws) {
    __shared__ float scurr[10 * NC];
    int bid = blockIdx.x, tid = threadIdx.x;
    int b = bid >> 4, tile = bid & 15;
    const float* cb = out + (size_t)b * 20 * NC;
    for (int i = tid; i < 10 * NC; i += 256) scurr[i] = cb[i];
    __syncthreads();
    int n = tile * 256 + tid;
    const float* fb = qf + (size_t)b * NC * HW + n;
    float acc[10] = {0, 0, 0, 0, 0, 0, 0, 0, 0, 0};
    for (int c = 0; c < NC; ++c) {
        float v = fb[(size_t)c * HW];
        #pragma unroll
        for (int i = 0; i < 10; ++i) acc[i] += scurr[i * NC + c] * v;
    }
    float fgv = ws[OFF_FG + b * HW + n] * SCL;
    float* al = ws + OFF_W2 + (size_t)b * 10 * HW;
    #pragma unroll
    for (int i = 0; i < 10; ++i) al[i * HW + n] = acc[i] * fgv;
}

// softmax over full 4096 row, then multiply by fg (folds the qf masking for apply)
__global__ __launch_bounds__(256) void k_softmax2(float* __restrict__ ws) {
    __shared__ float lds[8];
    int row = blockIdx.x, tid = threadIdx.x;
    int b = row / 10;
    float* al = ws + OFF_W2 + (size_t)row * HW;
    float vals[16];
    float mx[1] = {-3.0e38f};
    #pragma unroll
    for (int j = 0; j < 16; ++j) {
        vals[j] = al[tid + j * 256];
        mx[0] = fmaxf(mx[0], vals[j]);
    }
    blockReduceMaxN<1, 4>(mx, lds, tid);
    float sum[1] = {0.f};
    #pragma unroll
    for (int j = 0; j < 16; ++j) {
        vals[j] = expf(vals[j] - mx[0]);
        sum[0] += vals[j];
    }
    blockReduceSumN<1, 4>(sum, lds, tid);
    float inv = 1.f / sum[0];
    const float* fg = ws + OFF_FG + b * HW;
    #pragma unroll
    for (int j = 0; j < 16; ++j) {
        int n = tid + j * 256;
        al[n] = vals[j] * inv * fg[n];
    }
}

// mem rows 10..19: curr + sum_n w2[i][n]*qfeat[c][n]
__global__ __launch_bounds__(256) void k_apply2(const float* __restrict__ qf, float* __restrict__ ws,
                                                float* __restrict__ out) {
    __shared__ float lds[4 * 10];
    int bid = blockIdx.x, tid = threadIdx.x;
    int b = bid >> 8, c = bid & 255;
    const float* fb = qf + ((size_t)b * NC + c) * HW;
    const float* w2 = ws + OFF_W2 + (size_t)b * 10 * HW;
    float acc[10] = {0, 0, 0, 0, 0, 0, 0, 0, 0, 0};
    for (int j = 0; j < 16; ++j) {
        int n = tid + j * 256;
        float v = fb[n];
        #pragma unroll
        for (int i = 0; i < 10; ++i) acc[i] += w2[(size_t)i * HW + n] * v;
    }
    blockReduceSumN<10, 4>(acc, lds, tid);
    if (tid == 0) {
        float* ob = out + (size_t)b * 20 * NC;
        #pragma unroll
        for (int i = 0; i < 10; ++i)
            ob[(10 + i) * NC + c] = ob[i * NC + c] + acc[i];
    }
}

// curr_prototype = mean over 20 mem rows
__global__ __launch_bounds__(256) void k_mean(float* __restrict__ out) {
    int b = blockIdx.x, c = threadIdx.x;
    const float* ob = out + (size_t)b * 20 * NC;
    float s = 0.f;
    #pragma unroll
    for (int i = 0; i < 20; ++i) s += ob[i * NC + c];
    out[40960 + b * NC + c] = s * 0.05f;
}

extern "C" void kernel_launch(void* const* d_in, const int* in_sizes, int n_in,
                              void* d_out, int out_size, void* d_ws, size_t ws_size,
                              hipStream_t stream) {
    const float* f1  = (const float*)d_in[0];
    const float* f2  = (const float*)d_in[1];
    const int*   m1  = (const int*)d_in[2];
    const int*   m2  = (const int*)d_in[3];
    const float* qf  = (const float*)d_in[4];
    const float* qp  = (const float*)d_in[5];
    const float* Wq  = (const float*)d_in[6];
    const float* Wk  = (const float*)d_in[7];
    const float* Wv  = (const float*)d_in[8];
    const float* tok = (const float*)d_in[9];
    float* out = (float*)d_out;
    float* ws  = (float*)d_ws;

    k_prep<<<144, 256, 0, stream>>>(m1, m2, qp, ws);
    k_wqk<<<256, 256, 0, stream>>>(Wq, Wk, ws);
    k_proto<<<4096, 256, 0, stream>>>(f1, f2, m1, m2, ws);
    k_qk<<<16, 256, 0, stream>>>(tok, ws);
    k_attnlog<<<256, 256, 0, stream>>>(f1, f2, ws);
    k_sinkhorn<<<16, 256, 0, stream>>>(m1, m2, ws);
    k_ps<<<4096, 256, 0, stream>>>(f1, f2, ws);
    k_outproto<<<16, 256, 0, stream>>>(Wv, tok, ws, out);
    k_attn2log<<<128, 256, 0, stream>>>(qf, out, ws);
    k_softmax2<<<80, 256, 0, stream>>>(ws);
    k_apply2<<<2048, 256, 0, stream>>>(qf, ws, out);
    k_mean<<<8, 256, 0, stream>>>(out);
}

// Round 3
// 174.733 us; speedup vs baseline: 2.3448x; 1.2317x over previous
//
#include <hip/hip_runtime.h>
#include <hip/hip_bf16.h>
#include <math.h>

#define HW 4096
#define NC 256
#define NB 8
#define NA 5
#define NIT 24
#define SCL 0.0625f

// workspace layout (float offsets)
#define OFF_WQK   0                        // unused (kept for layout stability)
#define OFF_CNT   (OFF_WQK + 65536)        // unused
#define OFF_FG    (OFF_CNT + 16)           // 8*4096
#define OFF_PROTO (OFF_FG + 32768)         // 2*8*256
#define OFF_QK    (OFF_PROTO + 4096)       // 2*8*5*256
#define OFF_L     (OFF_QK + 20480)         // 2*8*5*4096
#define OFF_P     (OFF_L + 327680)         // 2*8*5*4096
#define OFF_PS    (OFF_P + 327680)         // 2*8*5*256
#define OFF_W2    (OFF_PS + 20480)         // 8*10*4096

__device__ inline float frcp(float x) { return __builtin_amdgcn_rcpf(x); }

// ---- DPP wave64 reductions: result valid in lane 63 ----
template<int NV>
__device__ inline void waveSum(float (&v)[NV]) {
    #pragma unroll
    for (int k = 0; k < NV; ++k) {
        float x = v[k]; int t;
        t = __builtin_amdgcn_update_dpp(0, __float_as_int(x), 0x111, 0xf, 0xf, true); x += __int_as_float(t);
        t = __builtin_amdgcn_update_dpp(0, __float_as_int(x), 0x112, 0xf, 0xf, true); x += __int_as_float(t);
        t = __builtin_amdgcn_update_dpp(0, __float_as_int(x), 0x114, 0xf, 0xf, true); x += __int_as_float(t);
        t = __builtin_amdgcn_update_dpp(0, __float_as_int(x), 0x118, 0xf, 0xf, true); x += __int_as_float(t);
        t = __builtin_amdgcn_update_dpp(0, __float_as_int(x), 0x142, 0xf, 0xf, true); x += __int_as_float(t);
        t = __builtin_amdgcn_update_dpp(0, __float_as_int(x), 0x143, 0xf, 0xf, true); x += __int_as_float(t);
        v[k] = x;
    }
}

template<int NV>
__device__ inline void waveMax(float (&v)[NV]) {
    #pragma unroll
    for (int k = 0; k < NV; ++k) {
        float x = v[k]; int t;
        t = __builtin_amdgcn_update_dpp(__float_as_int(x), __float_as_int(x), 0x111, 0xf, 0xf, false); x = fmaxf(x, __int_as_float(t));
        t = __builtin_amdgcn_update_dpp(__float_as_int(x), __float_as_int(x), 0x112, 0xf, 0xf, false); x = fmaxf(x, __int_as_float(t));
        t = __builtin_amdgcn_update_dpp(__float_as_int(x), __float_as_int(x), 0x114, 0xf, 0xf, false); x = fmaxf(x, __int_as_float(t));
        t = __builtin_amdgcn_update_dpp(__float_as_int(x), __float_as_int(x), 0x118, 0xf, 0xf, false); x = fmaxf(x, __int_as_float(t));
        t = __builtin_amdgcn_update_dpp(__float_as_int(x), __float_as_int(x), 0x142, 0xf, 0xf, false); x = fmaxf(x, __int_as_float(t));
        t = __builtin_amdgcn_update_dpp(__float_as_int(x), __float_as_int(x), 0x143, 0xf, 0xf, false); x = fmaxf(x, __int_as_float(t));
        v[k] = x;
    }
}

// cross-wave (4 waves, 256 threads): DPP wave reduce + one LDS round, ONE barrier.
template<int NV>
__device__ inline void crossSum4(float (&v)[NV], float* buf, int lane, int wid) {
    waveSum<NV>(v);
    if (lane == 63) {
        #pragma unroll
        for (int k = 0; k < NV; ++k) buf[wid * NV + k] = v[k];
    }
    __syncthreads();
    #pragma unroll
    for (int k = 0; k < NV; ++k)
        v[k] = buf[k] + buf[NV + k] + buf[2 * NV + k] + buf[3 * NV + k];
}

template<int NV>
__device__ inline void crossMax4(float (&v)[NV], float* buf, int lane, int wid) {
    waveMax<NV>(v);
    if (lane == 63) {
        #pragma unroll
        for (int k = 0; k < NV; ++k) buf[wid * NV + k] = v[k];
    }
    __syncthreads();
    #pragma unroll
    for (int k = 0; k < NV; ++k)
        v[k] = fmaxf(fmaxf(buf[k], buf[NV + k]), fmaxf(buf[2 * NV + k], buf[3 * NV + k]));
}

// proto[s][b][c] = masked mean over HW; count computed inline (mask is L2-hot)
__global__ __launch_bounds__(256) void k_proto(const float* __restrict__ f1, const float* __restrict__ f2,
                                               const int* __restrict__ m1, const int* __restrict__ m2,
                                               float* __restrict__ ws) {
    __shared__ float buf[8];
    int bid = blockIdx.x, tid = threadIdx.x;
    int lane = tid & 63, wid = tid >> 6;
    int s = bid >> 11, b = (bid >> 8) & 7, c = bid & 255;
    const float* f = s ? f2 : f1;
    const int* m = s ? m2 : m1;
    const float4* fb4 = (const float4*)(f + ((size_t)b * NC + c) * HW);
    const int4* mb4 = (const int4*)(m + b * HW);
    float v2[2] = {0.f, 0.f};   // masked sum, count
    #pragma unroll
    for (int j = 0; j < 4; ++j) {
        int idx = tid + j * 256;
        float4 v = fb4[idx];
        int4 mm = mb4[idx];
        if (mm.x == 1) { v2[0] += v.x; v2[1] += 1.f; }
        if (mm.y == 1) { v2[0] += v.y; v2[1] += 1.f; }
        if (mm.z == 1) { v2[0] += v.z; v2[1] += 1.f; }
        if (mm.w == 1) { v2[0] += v.w; v2[1] += 1.f; }
    }
    crossSum4<2>(v2, buf, lane, wid);
    if (tid == 0)
        ws[OFF_PROTO + (s * 8 + b) * NC + c] = v2[0] / (v2[1] + 1e-5f);
}

// fused: q = (proto+tok)@Wq^T ; qk = q@Wk   (one block per sb)
__global__ __launch_bounds__(256) void k_qk(const float* __restrict__ Wq, const float* __restrict__ Wk,
                                            const float* __restrict__ tok, float* __restrict__ ws) {
    __shared__ float sp3[NA * NC];
    __shared__ float tq[NA * NC];
    int sb = blockIdx.x, tid = threadIdx.x;
    const float* proto = ws + OFF_PROTO + sb * NC;
    for (int i = tid; i < NA * NC; i += 256) sp3[i] = proto[i & 255] + tok[i];
    __syncthreads();
    // stage 1: tq[a][tid] = sum_ci sp3[a][ci] * Wq[tid][ci]
    const float4* wq4 = (const float4*)(Wq + (size_t)tid * NC);
    float acc[NA] = {0, 0, 0, 0, 0};
    for (int c4 = 0; c4 < 64; ++c4) {
        float4 w = wq4[c4];
        #pragma unroll
        for (int a = 0; a < NA; ++a) {
            const float* sp = sp3 + a * NC + 4 * c4;
            acc[a] += sp[0] * w.x + sp[1] * w.y + sp[2] * w.z + sp[3] * w.w;
        }
    }
    #pragma unroll
    for (int a = 0; a < NA; ++a) tq[a * NC + tid] = acc[a];
    __syncthreads();
    // stage 2: qk[a][tid] = sum_co tq[a][co] * Wk[co][tid]
    float acc2[NA] = {0, 0, 0, 0, 0};
    #pragma unroll 4
    for (int co = 0; co < NC; ++co) {
        float w = Wk[(size_t)co * NC + tid];
        #pragma unroll
        for (int a = 0; a < NA; ++a) acc2[a] += tq[a * NC + co] * w;
    }
    float* qko = ws + OFF_QK + sb * NA * NC;
    #pragma unroll
    for (int a = 0; a < NA; ++a) qko[a * NC + tid] = acc2[a];
}

// L[s][b][a][n] = sum_c qk[a][c]*feat[c][n]
__global__ __launch_bounds__(256) void k_attnlog(const float* __restrict__ f1, const float* __restrict__ f2,
                                                 float* __restrict__ ws) {
    __shared__ float sqk[NA * NC];
    int bid = blockIdx.x, tid = threadIdx.x;
    int s = bid >> 7, b = (bid >> 4) & 7, tile = bid & 15;
    const float* f = s ? f2 : f1;
    int sb = s * 8 + b;
    const float* qkb = ws + OFF_QK + sb * NA * NC;
    for (int i = tid; i < NA * NC; i += 256) sqk[i] = qkb[i];
    __syncthreads();
    int n = tile * 256 + tid;
    const float* fb = f + (size_t)b * NC * HW + n;
    float acc[NA] = {0, 0, 0, 0, 0};
    #pragma unroll 4
    for (int c = 0; c < NC; ++c) {
        float v = fb[(size_t)c * HW];
        #pragma unroll
        for (int a = 0; a < NA; ++a) acc[a] += sqk[a * NC + c] * v;
    }
    float* Lb = ws + OFF_L + (size_t)sb * NA * HW;
    #pragma unroll
    for (int a = 0; a < NA; ++a) Lb[a * HW + n] = acc[a];
}

// masked softmax -> K=exp(2*attn-2)*mask -> NIT sinkhorn iters -> plan
// 256 threads, 16 cols/thread in registers, DPP reduce, 1 barrier/iter.
__global__ __launch_bounds__(256) void k_sinkhorn(const int* __restrict__ m1, const int* __restrict__ m2,
                                                  float* __restrict__ ws) {
    __shared__ float buf[2][24];
    int sb = blockIdx.x, tid = threadIdx.x;
    int lane = tid & 63, wid = tid >> 6;
    int s = sb >> 3, b = sb & 7;
    const int* m = (s ? m2 : m1) + b * HW;
    const float4* Lb4 = (const float4*)(ws + OFF_L + (size_t)sb * NA * HW);
    const int4* mb4 = (const int4*)m;

    unsigned mbits = 0;
    float K[NA][16];
    #pragma unroll
    for (int j = 0; j < 4; ++j) {
        int idx = tid + j * 256;
        int4 mm = mb4[idx];
        if (mm.x == 1) mbits |= 1u << (4 * j + 0);
        if (mm.y == 1) mbits |= 1u << (4 * j + 1);
        if (mm.z == 1) mbits |= 1u << (4 * j + 2);
        if (mm.w == 1) mbits |= 1u << (4 * j + 3);
        #pragma unroll
        for (int a = 0; a < NA; ++a) {
            float4 lv = Lb4[a * 1024 + idx];
            K[a][4 * j + 0] = lv.x; K[a][4 * j + 1] = lv.y;
            K[a][4 * j + 2] = lv.z; K[a][4 * j + 3] = lv.w;
        }
    }
    // masked row max
    float r[NA];
    #pragma unroll
    for (int a = 0; a < NA; ++a) {
        float mx = -3.0e38f;
        #pragma unroll
        for (int j = 0; j < 16; ++j)
            if ((mbits >> j) & 1) mx = fmaxf(mx, K[a][j]);
        r[a] = mx;
    }
    crossMax4<NA>(r, buf[0], lane, wid);
    // masked exp, row sums + count (popcount folded into same reduction)
    float rs6[6];
    #pragma unroll
    for (int a = 0; a < NA; ++a) {
        float sum = 0.f;
        #pragma unroll
        for (int j = 0; j < 16; ++j) {
            float e = ((mbits >> j) & 1) ? expf(K[a][j] - r[a]) : 0.f;
            K[a][j] = e; sum += e;
        }
        rs6[a] = sum;
    }
    rs6[5] = (float)__popc(mbits);
    crossSum4<6>(rs6, buf[1], lane, wid);
    float inv_cnt = frcp(rs6[5]);
    // K = mask * exp(2*softmax - 2)
    #pragma unroll
    for (int a = 0; a < NA; ++a) {
        float irs = frcp(rs6[a]);
        #pragma unroll
        for (int j = 0; j < 16; ++j) {
            float attn = K[a][j] * irs;
            K[a][j] = ((mbits >> j) & 1) ? expf(2.f * attn - 2.f) : 0.f;
        }
    }
    float u[NA];
    #pragma unroll
    for (int a = 0; a < NA; ++a) u[a] = 0.2f;
    for (int it = 0; it < NIT; ++it) {
        float part[NA] = {0, 0, 0, 0, 0};
        #pragma unroll
        for (int j = 0; j < 16; ++j) {
            float d = 0.f;
            #pragma unroll
            for (int a = 0; a < NA; ++a) d += K[a][j] * u[a];
            float t = inv_cnt * frcp(fmaxf(d, 1e-30f));
            #pragma unroll
            for (int a = 0; a < NA; ++a) part[a] += K[a][j] * t;
        }
        crossSum4<NA>(part, buf[it & 1], lane, wid);
        #pragma unroll
        for (int a = 0; a < NA; ++a) u[a] = 0.2f * frcp(fmaxf(part[a], 1e-30f));
    }
    float4* Pb4 = (float4*)(ws + OFF_P + (size_t)sb * NA * HW);
    #pragma unroll
    for (int j4 = 0; j4 < 4; ++j4) {
        int idx = tid + j4 * 256;
        float tcol[4];
        #pragma unroll
        for (int k = 0; k < 4; ++k) {
            int j = 4 * j4 + k;
            float d = 0.f;
            #pragma unroll
            for (int a = 0; a < NA; ++a) d += K[a][j] * u[a];
            tcol[k] = inv_cnt * frcp(fmaxf(d, 1e-30f));
        }
        #pragma unroll
        for (int a = 0; a < NA; ++a) {
            float4 o;
            o.x = u[a] * K[a][4 * j4 + 0] * tcol[0];
            o.y = u[a] * K[a][4 * j4 + 1] * tcol[1];
            o.z = u[a] * K[a][4 * j4 + 2] * tcol[2];
            o.w = u[a] * K[a][4 * j4 + 3] * tcol[3];
            Pb4[a * 1024 + idx] = o;
        }
    }
}

// ps[s][b][a][c] = sum_n P[a][n]*feat[c][n]
__global__ __launch_bounds__(256) void k_ps(const float* __restrict__ f1, const float* __restrict__ f2,
                                            float* __restrict__ ws) {
    __shared__ float buf[20];
    int bid = blockIdx.x, tid = threadIdx.x;
    int lane = tid & 63, wid = tid >> 6;
    int s = bid >> 11, b = (bid >> 8) & 7, c = bid & 255;
    const float* f = s ? f2 : f1;
    int sb = s * 8 + b;
    const float4* fb4 = (const float4*)(f + ((size_t)b * NC + c) * HW);
    const float4* Pb4 = (const float4*)(ws + OFF_P + (size_t)sb * NA * HW);
    float acc[NA] = {0, 0, 0, 0, 0};
    #pragma unroll
    for (int j = 0; j < 4; ++j) {
        int idx = tid + j * 256;
        float4 v = fb4[idx];
        #pragma unroll
        for (int a = 0; a < NA; ++a) {
            float4 p = Pb4[a * 1024 + idx];
            acc[a] += p.x * v.x + p.y * v.y + p.z * v.z + p.w * v.w;
        }
    }
    crossSum4<NA>(acc, buf, lane, wid);
    if (tid == 0) {
        float* ps = ws + OFF_PS + sb * NA * NC;
        #pragma unroll
        for (int a = 0; a < NA; ++a) ps[a * NC + c] = acc[a];
    }
}

// mem rows 0..9: proto3 + ps @ Wv^T
__global__ __launch_bounds__(256) void k_outproto(const float* __restrict__ Wv, const float* __restrict__ tok,
                                                  float* __restrict__ ws, float* __restrict__ out) {
    __shared__ float sps[NA * NC];
    int sb = blockIdx.x, tid = threadIdx.x;
    int s = sb >> 3, b = sb & 7;
    const float* ps = ws + OFF_PS + sb * NA * NC;
    for (int i = tid; i < NA * NC; i += 256) sps[i] = ps[i];
    __syncthreads();
    const float4* wv4 = (const float4*)(Wv + (size_t)tid * NC);
    float acc[NA] = {0, 0, 0, 0, 0};
    for (int c4 = 0; c4 < 64; ++c4) {
        float4 w = wv4[c4];
        #pragma unroll
        for (int a = 0; a < NA; ++a) {
            const float* sp = sps + a * NC + 4 * c4;
            acc[a] += sp[0] * w.x + sp[1] * w.y + sp[2] * w.z + sp[3] * w.w;
        }
    }
    float p = ws[OFF_PROTO + sb * NC + tid];
    #pragma unroll
    for (int a = 0; a < NA; ++a)
        out[(size_t)b * 20 * NC + (s * NA + a) * NC + tid] = p + tok[a * NC + tid] + acc[a];
}

// attn2 logits (fg computed inline and stored for softmax2)
__global__ __launch_bounds__(256) void k_attn2log(const float* __restrict__ qf, const float* __restrict__ qp,
                                                  const float* __restrict__ out, float* __restrict__ ws) {
    __shared__ float scurr[10 * NC];
    int bid = blockIdx.x, tid = threadIdx.x;
    int b = bid >> 4, tile = bid & 15;
    const float* cb = out + (size_t)b * 20 * NC;
    for (int i = tid; i < 10 * NC; i += 256) scurr[i] = cb[i];
    __syncthreads();
    int n = tile * 256 + tid;
    float p0 = qp[(size_t)(b * 2 + 0) * HW + n];
    float p1 = qp[(size_t)(b * 2 + 1) * HW + n];
    float fgv = 1.f / (1.f + expf(p0 - p1));
    if (fgv > 0.7f) fgv = 1.f;
    else if (fgv < 0.3f) fgv = 0.f;
    ws[OFF_FG + b * HW + n] = fgv;
    const float* fb = qf + (size_t)b * NC * HW + n;
    float acc[10] = {0, 0, 0, 0, 0, 0, 0, 0, 0, 0};
    #pragma unroll 4
    for (int c = 0; c < NC; ++c) {
        float v = fb[(size_t)c * HW];
        #pragma unroll
        for (int i = 0; i < 10; ++i) acc[i] += scurr[i * NC + c] * v;
    }
    float* al = ws + OFF_W2 + (size_t)b * 10 * HW;
    float sc = fgv * SCL;
    #pragma unroll
    for (int i = 0; i < 10; ++i) al[i * HW + n] = acc[i] * sc;
}

// softmax over full 4096 row, then multiply by fg
__global__ __launch_bounds__(256) void k_softmax2(float* __restrict__ ws) {
    __shared__ float buf[2][8];
    int row = blockIdx.x, tid = threadIdx.x;
    int lane = tid & 63, wid = tid >> 6;
    int b = row / 10;
    float* al = ws + OFF_W2 + (size_t)row * HW;
    float vals[16];
    float mx[1] = {-3.0e38f};
    #pragma unroll
    for (int j = 0; j < 16; ++j) {
        vals[j] = al[tid + j * 256];
        mx[0] = fmaxf(mx[0], vals[j]);
    }
    crossMax4<1>(mx, buf[0], lane, wid);
    float sum[1] = {0.f};
    #pragma unroll
    for (int j = 0; j < 16; ++j) {
        vals[j] = expf(vals[j] - mx[0]);
        sum[0] += vals[j];
    }
    crossSum4<1>(sum, buf[1], lane, wid);
    float inv = frcp(sum[0]);
    const float* fg = ws + OFF_FG + b * HW;
    #pragma unroll
    for (int j = 0; j < 16; ++j) {
        int n = tid + j * 256;
        al[n] = vals[j] * inv * fg[n];
    }
}

// mem rows 10..19 = rows 0..9 + attn@qf ; also curr_prototype mean (fused)
__global__ __launch_bounds__(256) void k_apply2(const float* __restrict__ qf, float* __restrict__ ws,
                                                float* __restrict__ out) {
    __shared__ float buf[40];
    int bid = blockIdx.x, tid = threadIdx.x;
    int lane = tid & 63, wid = tid >> 6;
    int b = bid >> 8, c = bid & 255;
    const float4* fb4 = (const float4*)(qf + ((size_t)b * NC + c) * HW);
    const float4* w24 = (const float4*)(ws + OFF_W2 + (size_t)b * 10 * HW);
    float acc[10] = {0, 0, 0, 0, 0, 0, 0, 0, 0, 0};
    #pragma unroll
    for (int j = 0; j < 4; ++j) {
        int idx = tid + j * 256;
        float4 v = fb4[idx];
        #pragma unroll
        for (int i = 0; i < 10; ++i) {
            float4 w = w24[i * 1024 + idx];
            acc[i] += w.x * v.x + w.y * v.y + w.z * v.z + w.w * v.w;
        }
    }
    crossSum4<10>(acc, buf, lane, wid);
    if (tid == 0) {
        float* ob = out + (size_t)b * 20 * NC;
        float stot = 0.f;
        #pragma unroll
        for (int i = 0; i < 10; ++i) {
            float base = ob[i * NC + c];
            float r = base + acc[i];
            ob[(10 + i) * NC + c] = r;
            stot += base + r;
        }
        out[40960 + b * NC + c] = stot * 0.05f;   // mean over 20 rows
    }
}

extern "C" void kernel_launch(void* const* d_in, const int* in_sizes, int n_in,
                              void* d_out, int out_size, void* d_ws, size_t ws_size,
                              hipStream_t stream) {
    const float* f1  = (const float*)d_in[0];
    const float* f2  = (const float*)d_in[1];
    const int*   m1  = (const int*)d_in[2];
    const int*   m2  = (const int*)d_in[3];
    const float* qf  = (const float*)d_in[4];
    const float* qp  = (const float*)d_in[5];
    const float* Wq  = (const float*)d_in[6];
    const float* Wk  = (const float*)d_in[7];
    const float* Wv  = (const float*)d_in[8];
    const float* tok = (const float*)d_in[9];
    float* out = (float*)d_out;
    float* ws  = (float*)d_ws;

    k_proto<<<4096, 256, 0, stream>>>(f1, f2, m1, m2, ws);
    k_qk<<<16, 256, 0, stream>>>(Wq, Wk, tok, ws);
    k_attnlog<<<256, 256, 0, stream>>>(f1, f2, ws);
    k_sinkhorn<<<16, 256, 0, stream>>>(m1, m2, ws);
    k_ps<<<4096, 256, 0, stream>>>(f1, f2, ws);
    k_outproto<<<16, 256, 0, stream>>>(Wv, tok, ws, out);
    k_attn2log<<<128, 256, 0, stream>>>(qf, qp, out, ws);
    k_softmax2<<<80, 256, 0, stream>>>(ws);
    k_apply2<<<2048, 256, 0, stream>>>(qf, ws, out);
}